// Round 6
// baseline (86.007 us; speedup 1.0000x reference)
//
#include <hip/hip_runtime.h>
#include <cstdint>

// ---- problem constants ----
#define B_ROWS 8192
#define XSTR   406      // x row stride (ints)
#define GAMMA_C 12.0f
#define SCALE_ANG 30.994217f   // PI / sqrt(6/584)

#define KH     1024            // padded t-range (1000 -> 1024)

// prep grid partition (order: H | temb | Agather | tab | wcat)
#define NH_BLK 4096            // H build: 4 row-ents/block
#define NS_BLK 8192            // t_emb: 2 row-ents/block
#define NA_BLK 2048            // A gather: 8 row-ents/block
#define NT_BLK 128             // tab frags: 4/block (512)
#define NW_BLK 64              // wcat frags: 4/block (256)
#define NPREP  (NH_BLK + NS_BLK + NA_BLK + NT_BLK + NW_BLK)

// workspace layout (full path)
#define TF_BYTES    (KH*256*2)          // 524288   : tab, B-frag order
#define WCAT_BYTES  (512*256*2)         // 262144   : sign-folded w_e, B-frag order
#define H_BYTES     (16384*KH*2)        // 33554432 : histogram bf16
#define P_BYTES     (16384*256*4)       // 16777216 : GEMM out f32 (p + P3)
#define STB_BYTES   (16384*256*2)       // 8388608  : t_emb bf16
#define AB_BYTES    (16384*512*2)       // 16777216 : e_emb rows bf16
#define WS_FULL     ((size_t)(TF_BYTES + WCAT_BYTES + H_BYTES + P_BYTES + STB_BYTES + AB_BYTES))
// round-3 fallback path
#define OLDTAB_BYTES (1000*256*2)
#define WS_OLD       ((size_t)(OLDTAB_BYTES + WCAT_BYTES))

typedef __attribute__((ext_vector_type(8))) short short8v;
typedef __attribute__((ext_vector_type(4))) float float4v;

__device__ __forceinline__ float bfLo(uint32_t u) { return __uint_as_float(u << 16); }
__device__ __forceinline__ float bfHi(uint32_t u) { return __uint_as_float(u & 0xffff0000u); }
__device__ __forceinline__ float bf1(unsigned short u) { return __uint_as_float((uint32_t)u << 16); }

__device__ __forceinline__ uint32_t f2bf_u(float x) {
  uint32_t u = __float_as_uint(x);
  u += 0x7fffu + ((u >> 16) & 1u);   // RNE
  return u >> 16;
}
__device__ __forceinline__ unsigned short f2bf(float x) { return (unsigned short)f2bf_u(x); }

// ---------------------------------------------------------------------------
// Stage 1: all random gathers + table builds, one grid.
// B-frag swizzle: frag fb, lane l, elem j <-> k=(fb>>4)*32+(l>>4)*8+j, c=(fb&15)*16+(l&15)
__global__ __launch_bounds__(256) void kge_prep(
    const int* __restrict__ x, const float* __restrict__ w_rp,
    const float* __restrict__ w_e, const float* __restrict__ e_emb,
    const float* __restrict__ d_frq, const float* __restrict__ d_phi, const float* __restrict__ d_amp,
    const float* __restrict__ m_frq, const float* __restrict__ m_phi, const float* __restrict__ m_amp,
    unsigned short* __restrict__ tf, unsigned short* __restrict__ wcat,
    unsigned short* __restrict__ H, unsigned short* __restrict__ stbuf,
    unsigned short* __restrict__ abuf) {
  __shared__ float Hl[4][KH];
  const int bid = blockIdx.x;
  const int tid = threadIdx.x;
  const int sub = tid >> 6, l = tid & 63;

  if (bid < NH_BLK) {
    // ---- H[re][t] = sum_{n: c_{re,n}=t} w_rp[rid][n]; wave-local scatter ----
    const int re = bid * 4 + sub;
    const int row = re >> 1, ent = re & 1;
    float4 z = {0, 0, 0, 0};
    for (int i = l; i < KH / 4; i += 64) ((float4*)Hl[sub])[i] = z;
    const int rid = x[(size_t)row * XSTR + 1];
    const int* cp = x + (size_t)row * XSTR + 6 + ent * 200;
    const float* wp = w_rp + (size_t)rid * 200;
    for (int n = l; n < 200; n += 64)
      atomicAdd(&Hl[sub][cp[n]], wp[n]);
    unsigned short* dst = H + (size_t)re * KH;
    for (int i = l; i < KH / 2; i += 64) {
      float a = Hl[sub][2 * i], b = Hl[sub][2 * i + 1];
      ((uint32_t*)dst)[i] = f2bf_u(a) | (f2bf_u(b) << 16);
    }
  } else if (bid < NH_BLK + NS_BLK) {
    // ---- t_emb -> stbuf (2 ents/block; 128 pair-threads per ent) ----
    const int ee = (bid - NH_BLK) * 2 + (tid >> 7);
    const int jj = tid & 127;
    const int row = ee >> 1, es = ee & 1;
    const int* xr = x + (size_t)row * XSTR;
    const int e = xr[es ? 2 : 0];
    const float dv = (float)xr[3], mv = (float)xr[4];
    const int j = 2 * jj;
    float2 fd = *(const float2*)&d_frq[(size_t)e * 256 + j];
    float2 pd = *(const float2*)&d_phi[(size_t)e * 256 + j];
    float2 fm = *(const float2*)&m_frq[(size_t)e * 256 + j];
    float2 pm = *(const float2*)&m_phi[(size_t)e * 256 + j];
    const int ja = j & 127;
    float2 ad = *(const float2*)&d_amp[(size_t)e * 128 + ja];
    float2 am = *(const float2*)&m_amp[(size_t)e * 128 + ja];
    float a0 = fmaf(dv, fd.x, pd.x), a1 = fmaf(dv, fd.y, pd.y);
    float b0 = fmaf(mv, fm.x, pm.x), b1 = fmaf(mv, fm.y, pm.y);
    float t0, t1, u0, u1;
    if (j < 128) { t0 = __cosf(a0); t1 = __cosf(a1); u0 = __cosf(b0); u1 = __cosf(b1); }
    else         { t0 = __sinf(a0); t1 = __sinf(a1); u0 = __sinf(b0); u1 = __sinf(b1); }
    float v0 = fmaf(ad.x, t0, am.x * u0);
    float v1 = fmaf(ad.y, t1, am.y * u1);
    *(uint32_t*)&stbuf[(size_t)ee * 256 + j] = f2bf_u(v0) | (f2bf_u(v1) << 16);
  } else if (bid < NH_BLK + NS_BLK + NA_BLK) {
    // ---- e_emb gather -> abuf bf16 (8 ent-rows/block; 32 threads/row) ----
    const int re = (bid - NH_BLK - NS_BLK) * 8 + (tid >> 5);
    const int seg = tid & 31;
    const int row = re >> 1;
    const int e = x[(size_t)row * XSTR + ((re & 1) ? 2 : 0)];
    const float4* src = (const float4*)e_emb + (size_t)e * 128;
    uint2* dst = (uint2*)(abuf + (size_t)re * 512);
    #pragma unroll
    for (int q = 0; q < 4; ++q) {
      float4 v = src[seg * 4 + q];
      uint2 pk;
      pk.x = f2bf_u(v.x) | (f2bf_u(v.y) << 16);
      pk.y = f2bf_u(v.z) | (f2bf_u(v.w) << 16);
      dst[seg * 4 + q] = pk;
    }
  } else if (bid < NH_BLK + NS_BLK + NA_BLK + NT_BLK) {
    // ---- tab frags: value(k,c) = k<1000 ? (c<128 ? cos : sin)(k*f_{c&127}) : 0
    const int fragid = (bid - NH_BLK - NS_BLK - NA_BLK) * 4 + sub;   // kt*16+nt
    const int kt = fragid >> 4, nt = fragid & 15;
    const int c = nt * 16 + (l & 15);
    const float f = exp2f(-(float)(c & 127) * (13.287712379549449f / 128.f));
    __align__(16) unsigned short v[8];
    #pragma unroll
    for (int j = 0; j < 8; ++j) {
      int k = kt * 32 + ((l >> 4) << 3) + j;
      float val = 0.f;
      if (k < 1000) {
        float s, cv;
        sincosf((float)k * f, &s, &cv);
        val = (c < 128) ? cv : s;
      }
      v[j] = f2bf(val);
    }
    ((uint4*)tf)[fragid * 64 + l] = *(const uint4*)v;
  } else {
    // ---- Wcat frags: Wcat[k][c] = c<128 ? s(k)*w_e[k][c] : -s(k)*w_e[k^256][c-128]
    const int fragid = (bid - NH_BLK - NS_BLK - NA_BLK - NT_BLK) * 4 + sub;
    const int kk = fragid >> 4, nt = fragid & 15;
    const int c = nt * 16 + (l & 15);
    __align__(16) unsigned short v[8];
    #pragma unroll
    for (int j = 0; j < 8; ++j) {
      int k = kk * 32 + ((l >> 4) << 3) + j;
      float s = (k < 256) ? 1.f : -1.f;
      float val = (c < 128) ? s * w_e[k * 128 + c]
                            : -s * w_e[(k ^ 256) * 128 + (c - 128)];
      v[j] = f2bf(val);
    }
    ((uint4*)wcat)[fragid * 64 + l] = *(const uint4*)v;
  }
}

// ---------------------------------------------------------------------------
// Stage 2: Pfull(16384x256,f32) = [Abuf(512) | H(1024)] @ [Wcat ; tab]  (K=1536)
// grid (128, 2); M-tile 128 (8 waves x 16 rows), N-tile 128.
// Double-buffered B staging, one barrier per K-step (validated scheme).
__global__ __launch_bounds__(512) void kge_gemm2(
    const unsigned short* __restrict__ Ab, const unsigned short* __restrict__ H,
    const unsigned short* __restrict__ wcat, const unsigned short* __restrict__ tf,
    float* __restrict__ P) {
  __shared__ __align__(16) uint4 bb[2][512];
  const int tid = threadIdx.x;
  const int w = tid >> 6, l = tid & 63;
  const int m0 = blockIdx.x * 128 + w * 16;
  const int nb = blockIdx.y;
  float4v acc[8];
  #pragma unroll
  for (int i = 0; i < 8; ++i) acc[i] = (float4v){0, 0, 0, 0};

  const uint4* wq = (const uint4*)wcat;
  const uint4* tq = (const uint4*)tf;
  const int fsub = tid >> 6, flane = tid & 63;
  const unsigned short* arowA = Ab + (size_t)(m0 + (l & 15)) * 512 + ((l >> 4) << 3);
  const unsigned short* arowH = H + (size_t)(m0 + (l & 15)) * KH + ((l >> 4) << 3);

  // prologue: stage kt=0 (a Wcat step)
  bb[0][tid] = wq[(size_t)(nb * 8 + fsub) * 64 + flane];
  for (int kt = 0; kt < 48; ++kt) {
    const int cur = kt & 1;
    uint4 rg;
    if (kt < 47) {
      const int kn = kt + 1;
      rg = (kn < 16) ? wq[(size_t)(kn * 16 + nb * 8 + fsub) * 64 + flane]
                     : tq[(size_t)((kn - 16) * 16 + nb * 8 + fsub) * 64 + flane];
    }
    __syncthreads();
    short8v a = (kt < 16) ? *(const short8v*)(arowA + kt * 32)
                          : *(const short8v*)(arowH + (kt - 16) * 32);
    #pragma unroll
    for (int nt = 0; nt < 8; ++nt) {
      short8v b = *(const short8v*)&bb[cur][nt * 64 + l];
      acc[nt] = __builtin_amdgcn_mfma_f32_16x16x32_bf16(a, b, acc[nt], 0, 0, 0);
    }
    if (kt < 47) bb[cur ^ 1][tid] = rg;
  }
  const int col0 = nb * 128 + (l & 15);
  const int r0 = m0 + ((l >> 4) << 2);
  #pragma unroll
  for (int nt = 0; nt < 8; ++nt)
    #pragma unroll
    for (int q = 0; q < 4; ++q)
      P[(size_t)(r0 + q) * 256 + col0 + nt * 16] = acc[nt][q];
}

// ---------------------------------------------------------------------------
// Stage 3: scores. Pure streaming, no LDS. 8 rows/block, wave w -> row w.
__global__ __launch_bounds__(512) void kge_score(
    const int* __restrict__ x, const float* __restrict__ r_emb,
    const unsigned short* __restrict__ Ab, const unsigned short* __restrict__ stbuf,
    const float* __restrict__ P, float* __restrict__ out) {
  const int tid = threadIdx.x;
  const int w = tid >> 6, l = tid & 63;
  const int row = blockIdx.x * 8 + w;
  const int rid = __builtin_amdgcn_readfirstlane(x[(size_t)row * XSTR + 1]);
  const int reS = row * 2, reO = reS + 1;
  const unsigned short* As = Ab + (size_t)reS * 512;
  const unsigned short* Ao = Ab + (size_t)reO * 512;
  const unsigned short* Ss = stbuf + (size_t)reS * 256;
  const unsigned short* So = stbuf + (size_t)reO * 256;
  const float* Ps = P + (size_t)reS * 256;
  const float* Po = P + (size_t)reO * 256;

  float sabs = 0.f;
  #pragma unroll
  for (int u0 = 0; u0 < 384; u0 += 64) {
    const int u = u0 + l;
    float ang = r_emb[(size_t)rid * 384 + u] * SCALE_ANG;
    float sr = __sinf(ang), cr = __cosf(ang);
    float res, ims, reo, imo;
    if (u0 < 256) {
      res = bf1(As[u]);       ims = bf1(As[256 + u]);
      reo = bf1(Ao[u]);       imo = bf1(Ao[256 + u]);
    } else {
      const int uu = u - 256;
      res = bf1(Ss[uu]);      ims = bf1(Ss[128 + uu]);
      reo = bf1(So[uu]);      imo = bf1(So[128 + uu]);
    }
    float rsc = res * cr - ims * sr - reo;
    float isc = res * sr + ims * cr - imo;
    sabs += sqrtf(rsc * rsc + isc * isc);
  }
  float srel = 0.f;
  #pragma unroll
  for (int u0 = 0; u0 < 128; u0 += 64) {
    const int u = u0 + l;
    float dre = Ps[u] - Po[u];
    float dim = Ps[128 + u] - Po[128 + u];
    srel += sqrtf(dre * dre + dim * dim);
  }
  float tot = sabs + srel;
  #pragma unroll
  for (int off = 32; off > 0; off >>= 1) tot += __shfl_down(tot, off);
  if (l == 0) out[row] = GAMMA_C - tot;
}

// ===========================================================================
// Round-3 fallback path (workspace >= 774 KB but < WS_FULL)
#define NTH    512
#define RPB    8
#define ERB    (2*RPB)
#define APAD   520

__global__ void kge_table_old(unsigned short* __restrict__ tab) {
  int t = blockIdx.x;
  int j = threadIdx.x;
  double f = pow(10000.0, -(double)j / 128.0);
  double ang = (double)t * f;
  int q = j >> 1, lo = j & 1;
  tab[t * 256 + 4 * q + lo]     = f2bf((float)cos(ang));
  tab[t * 256 + 4 * q + 2 + lo] = f2bf((float)sin(ang));
}

__global__ void kge_wcat_old(const float* __restrict__ w_e, unsigned short* __restrict__ wcat) {
  int bid = blockIdx.x;
  int kk = bid >> 4, nt = bid & 15;
  int l = threadIdx.x;
  __align__(16) unsigned short v[8];
  int c = nt * 16 + (l & 15);
  #pragma unroll
  for (int j = 0; j < 8; ++j) {
    int k = kk * 32 + ((l >> 4) << 3) + j;
    float s = (k < 256) ? 1.f : -1.f;
    float val = (c < 128) ? s * w_e[k * 128 + c]
                          : -s * w_e[(k ^ 256) * 128 + (c - 128)];
    v[j] = f2bf(val);
  }
  ((uint4*)wcat)[bid * 64 + l] = *(const uint4*)v;
}

__global__ __launch_bounds__(NTH, 4) void kge_main3(
    const int* __restrict__ x,
    const float* __restrict__ e_emb, const float* __restrict__ r_emb,
    const float* __restrict__ d_frq, const float* __restrict__ d_phi, const float* __restrict__ d_amp,
    const float* __restrict__ m_frq, const float* __restrict__ m_phi, const float* __restrict__ m_amp,
    const float* __restrict__ w_rp,
    const unsigned short* __restrict__ tab, const unsigned short* __restrict__ wcat,
    float* __restrict__ out) {
  __shared__ __align__(16) unsigned short A[ERB][APAD];
  __shared__ __align__(16) unsigned short stb[ERB][256];
  __shared__ __align__(16) float p[ERB][256];
  __shared__ int meta[RPB][6];

  const int tid = threadIdx.x;
  const int base_row = blockIdx.x * RPB;
  const int w = tid >> 6, l = tid & 63;

  if (tid < RPB * 6) {
    int r = tid / 6, f = tid % 6;
    meta[r][f] = x[(size_t)(base_row + r) * XSTR + f];
  }
  __syncthreads();

  for (int i = tid; i < ERB * 128; i += NTH) {
    int er = i >> 7, k4 = i & 127;
    int e = (er & 1) ? meta[er >> 1][2] : meta[er >> 1][0];
    float4 v = ((const float4*)e_emb)[(size_t)e * 128 + k4];
    uint2 pk;
    pk.x = f2bf_u(v.x) | (f2bf_u(v.y) << 16);
    pk.y = f2bf_u(v.z) | (f2bf_u(v.w) << 16);
    *(uint2*)&A[er][k4 * 4] = pk;
  }
  for (int it = tid; it < ERB * 256; it += NTH) {
    int j = it & 255, er = it >> 8, r = er >> 1;
    int e = (er & 1) ? meta[r][2] : meta[r][0];
    float dv = (float)meta[r][3], mv = (float)meta[r][4];
    size_t b256 = (size_t)e * 256 + j, b128 = (size_t)e * 128 + (j & 127);
    float argd = fmaf(dv, d_frq[b256], d_phi[b256]);
    float argm = fmaf(mv, m_frq[b256], m_phi[b256]);
    float vd = (j < 128) ? d_amp[b128] * __cosf(argd) : d_amp[b128] * __sinf(argd);
    float vm = (j < 128) ? m_amp[b128] * __cosf(argm) : m_amp[b128] * __sinf(argm);
    stb[er][j] = f2bf(vd + vm);
  }

  float s0 = 0, s1 = 0, s2 = 0, s3 = 0, o0 = 0, o1 = 0, o2 = 0, o3 = 0;
  {
    const int wu  = __builtin_amdgcn_readfirstlane(w);
    const int rid = __builtin_amdgcn_readfirstlane(meta[wu][1]);
    const int*   cp = x + (size_t)(base_row + wu) * XSTR + 6;
    const float* wp = w_rp + (size_t)rid * 200;
    const uint2* tl = ((const uint2*)tab) + l;
    #pragma unroll 2
    for (int n = 0; n < 200; ++n) {
      float wv = wp[n];
      int cS = cp[n];
      int cO = cp[200 + n];
      uint2 qs = tl[(size_t)cS * 64];
      uint2 qo = tl[(size_t)cO * 64];
      s0 = fmaf(wv, bfLo(qs.x), s0); s1 = fmaf(wv, bfHi(qs.x), s1);
      s2 = fmaf(wv, bfLo(qs.y), s2); s3 = fmaf(wv, bfHi(qs.y), s3);
      o0 = fmaf(wv, bfLo(qo.x), o0); o1 = fmaf(wv, bfHi(qo.x), o1);
      o2 = fmaf(wv, bfLo(qo.y), o2); o3 = fmaf(wv, bfHi(qo.y), o3);
    }
  }
  __syncthreads();

  {
    float4v acc0 = {0, 0, 0, 0}, acc1 = {0, 0, 0, 0};
    const int nt0 = 2 * w, nt1 = 2 * w + 1;
    const short8v* bp = (const short8v*)wcat;
    const unsigned short* arow = &A[l & 15][(l >> 4) << 3];
    #pragma unroll 8
    for (int kk = 0; kk < 16; ++kk) {
      short8v a  = *(const short8v*)(arow + kk * 32);
      short8v b0 = bp[(kk * 16 + nt0) * 64 + l];
      short8v b1 = bp[(kk * 16 + nt1) * 64 + l];
      acc0 = __builtin_amdgcn_mfma_f32_16x16x32_bf16(a, b0, acc0, 0, 0, 0);
      acc1 = __builtin_amdgcn_mfma_f32_16x16x32_bf16(a, b1, acc1, 0, 0, 0);
    }
    int col = l & 15, rbase = (l >> 4) * 4;
    #pragma unroll
    for (int q = 0; q < 4; ++q) {
      p[rbase + q][nt0 * 16 + col] = acc0[q];
      p[rbase + q][nt1 * 16 + col] = acc1[q];
    }
  }
  __syncthreads();

  {
    int es = 2 * w, eo = 2 * w + 1;
    p[es][2 * l] += s0; p[es][2 * l + 1] += s1;
    p[es][128 + 2 * l] += s2; p[es][129 + 2 * l] += s3;
    p[eo][2 * l] += o0; p[eo][2 * l + 1] += o1;
    p[eo][128 + 2 * l] += o2; p[eo][129 + 2 * l] += o3;
  }
  __syncthreads();

  {
    int r = w;
    int rid = meta[r][1];
    float sabs = 0.f;
    #pragma unroll
    for (int u0 = 0; u0 < 384; u0 += 64) {
      int u = u0 + l;
      float ang = r_emb[(size_t)rid * 384 + u] * SCALE_ANG;
      float sr = __sinf(ang), cr = __cosf(ang);
      float res, ims, reo, imo;
      if (u < 256) {
        res = bf1(A[2 * r][u]);       ims = bf1(A[2 * r][256 + u]);
        reo = bf1(A[2 * r + 1][u]);   imo = bf1(A[2 * r + 1][256 + u]);
      } else {
        int uu = u - 256;
        res = bf1(stb[2 * r][uu]);     ims = bf1(stb[2 * r][128 + uu]);
        reo = bf1(stb[2 * r + 1][uu]); imo = bf1(stb[2 * r + 1][128 + uu]);
      }
      float rsc = res * cr - ims * sr - reo;
      float isc = res * sr + ims * cr - imo;
      sabs += sqrtf(rsc * rsc + isc * isc);
    }
    float srel = 0.f;
    #pragma unroll
    for (int u0 = 0; u0 < 128; u0 += 64) {
      int u = u0 + l;
      float dre = p[2 * r][u] - p[2 * r + 1][u];
      float dim = p[2 * r][128 + u] - p[2 * r + 1][128 + u];
      srel += sqrtf(dre * dre + dim * dim);
    }
    float tot = sabs + srel;
    #pragma unroll
    for (int off = 32; off > 0; off >>= 1) tot += __shfl_down(tot, off);
    if (l == 0) out[base_row + r] = GAMMA_C - tot;
  }
}

// ===========================================================================
extern "C" void kernel_launch(void* const* d_in, const int* in_sizes, int n_in,
                              void* d_out, int out_size, void* d_ws, size_t ws_size,
                              hipStream_t stream) {
  (void)in_sizes; (void)n_in; (void)out_size;
  const int*   x     = (const int*)d_in[0];
  const float* e_emb = (const float*)d_in[1];
  const float* r_emb = (const float*)d_in[2];
  const float* d_frq = (const float*)d_in[3];
  const float* d_phi = (const float*)d_in[4];
  const float* d_amp = (const float*)d_in[5];
  const float* m_frq = (const float*)d_in[6];
  const float* m_phi = (const float*)d_in[7];
  const float* m_amp = (const float*)d_in[8];
  const float* w_e   = (const float*)d_in[9];
  const float* w_rp  = (const float*)d_in[10];
  float* out = (float*)d_out;

  if (ws_size >= WS_FULL) {
    char* base = (char*)d_ws;
    unsigned short* tf    = (unsigned short*)base;
    unsigned short* wcat  = (unsigned short*)(base + TF_BYTES);
    unsigned short* H     = (unsigned short*)(base + TF_BYTES + WCAT_BYTES);
    float*          P     = (float*)(base + TF_BYTES + WCAT_BYTES + H_BYTES);
    unsigned short* stbuf = (unsigned short*)(base + TF_BYTES + WCAT_BYTES + H_BYTES + P_BYTES);
    unsigned short* abuf  = (unsigned short*)(base + TF_BYTES + WCAT_BYTES + H_BYTES + P_BYTES + STB_BYTES);
    kge_prep<<<dim3(NPREP), dim3(256), 0, stream>>>(
        x, w_rp, w_e, e_emb, d_frq, d_phi, d_amp, m_frq, m_phi, m_amp,
        tf, wcat, H, stbuf, abuf);
    kge_gemm2<<<dim3(128, 2), dim3(512), 0, stream>>>(abuf, H, wcat, tf, P);
    kge_score<<<dim3(B_ROWS / 8), dim3(512), 0, stream>>>(x, r_emb, abuf, stbuf, P, out);
  } else if (ws_size >= WS_OLD) {
    unsigned short* tab  = (unsigned short*)d_ws;
    unsigned short* wcat = (unsigned short*)((char*)d_ws + OLDTAB_BYTES);
    kge_table_old<<<dim3(1000), dim3(128), 0, stream>>>(tab);
    kge_wcat_old<<<dim3(256), dim3(64), 0, stream>>>(w_e, wcat);
    kge_main3<<<dim3(B_ROWS / RPB), dim3(NTH), 0, stream>>>(
        x, e_emb, r_emb, d_frq, d_phi, d_amp, m_frq, m_phi, m_amp, w_rp,
        tab, wcat, out);
  }
}

// Round 8
// 85.727 us; speedup vs baseline: 1.0033x; 1.0033x over previous
//
#include <hip/hip_runtime.h>
#include <cstdint>

// ---- problem constants ----
#define B_ROWS 8192
#define XSTR   406      // x row stride (ints)
#define GAMMA_C 12.0f
#define SCALE_ANG 30.994217f   // PI / sqrt(6/584)

#define KH     1024            // padded t-range (1000 -> 1024)

// prep grid partition (order: H | temb | tab | wcat)
#define NH_BLK 4096            // H build: 4 row-ents/block
#define NS_BLK 8192            // t_emb: 2 row-ents/block
#define NT_BLK 128             // tab frags: 4/block (512)
#define NW_BLK 64              // wcat frags: 4/block (256)
#define NPREP  (NH_BLK + NS_BLK + NT_BLK + NW_BLK)

// workspace layout (full path)
#define TF_BYTES    (KH*256*2)          // 524288   : tab, B-frag order (k-step contiguous)
#define WCAT_BYTES  (512*256*2)         // 262144   : sign-folded w_e, B-frag order
#define H_BYTES     (16384*KH*2)        // 33554432 : histogram bf16
#define STB_BYTES   (16384*256*2)       // 8388608  : t_emb bf16
#define WS_FULL     ((size_t)(TF_BYTES + WCAT_BYTES + H_BYTES + STB_BYTES))
// round-3 fallback path
#define OLDTAB_BYTES (1000*256*2)
#define WS_OLD       ((size_t)(OLDTAB_BYTES + WCAT_BYTES))

typedef __attribute__((ext_vector_type(8))) short short8v;
typedef __attribute__((ext_vector_type(4))) float float4v;

__device__ __forceinline__ float bfLo(uint32_t u) { return __uint_as_float(u << 16); }
__device__ __forceinline__ float bfHi(uint32_t u) { return __uint_as_float(u & 0xffff0000u); }
__device__ __forceinline__ float bf1(unsigned short u) { return __uint_as_float((uint32_t)u << 16); }

__device__ __forceinline__ uint32_t f2bf_u(float x) {
  uint32_t u = __float_as_uint(x);
  u += 0x7fffu + ((u >> 16) & 1u);   // RNE
  return u >> 16;
}
__device__ __forceinline__ unsigned short f2bf(float x) { return (unsigned short)f2bf_u(x); }

__device__ __forceinline__ short8v cvt8(float4 a, float4 b) {
  short8v r;
  r[0] = (short)f2bf(a.x); r[1] = (short)f2bf(a.y);
  r[2] = (short)f2bf(a.z); r[3] = (short)f2bf(a.w);
  r[4] = (short)f2bf(b.x); r[5] = (short)f2bf(b.y);
  r[6] = (short)f2bf(b.z); r[7] = (short)f2bf(b.w);
  return r;
}

// ---------------------------------------------------------------------------
// Stage 1: random gathers + table builds.
// B-frag swizzle: frag fb, lane l, elem j <-> k=(fb>>4)*32+(l>>4)*8+j, c=(fb&15)*16+(l&15)
__global__ __launch_bounds__(256) void kge_prep(
    const int* __restrict__ x, const float* __restrict__ w_rp,
    const float* __restrict__ w_e,
    const float* __restrict__ d_frq, const float* __restrict__ d_phi, const float* __restrict__ d_amp,
    const float* __restrict__ m_frq, const float* __restrict__ m_phi, const float* __restrict__ m_amp,
    unsigned short* __restrict__ tf, unsigned short* __restrict__ wcat,
    unsigned short* __restrict__ H, unsigned short* __restrict__ stbuf) {
  __shared__ float Hl[4][KH];
  const int bid = blockIdx.x;
  const int tid = threadIdx.x;
  const int sub = tid >> 6, l = tid & 63;

  if (bid < NH_BLK) {
    // ---- H[re][t] = sum_{n: c_{re,n}=t} w_rp[rid][n]; wave-local scatter ----
    const int re = bid * 4 + sub;
    const int row = re >> 1, ent = re & 1;
    float4 z = {0, 0, 0, 0};
    for (int i = l; i < KH / 4; i += 64) ((float4*)Hl[sub])[i] = z;
    const int rid = x[(size_t)row * XSTR + 1];
    const int* cp = x + (size_t)row * XSTR + 6 + ent * 200;
    const float* wp = w_rp + (size_t)rid * 200;
    for (int n = l; n < 200; n += 64)
      atomicAdd(&Hl[sub][cp[n]], wp[n]);
    unsigned short* dst = H + (size_t)re * KH;
    for (int i = l; i < KH / 2; i += 64) {
      float a = Hl[sub][2 * i], b = Hl[sub][2 * i + 1];
      ((uint32_t*)dst)[i] = f2bf_u(a) | (f2bf_u(b) << 16);
    }
  } else if (bid < NH_BLK + NS_BLK) {
    // ---- t_emb -> stbuf (2 ents/block; 128 pair-threads per ent) ----
    const int ee = (bid - NH_BLK) * 2 + (tid >> 7);
    const int jj = tid & 127;
    const int row = ee >> 1, es = ee & 1;
    const int* xr = x + (size_t)row * XSTR;
    const int e = xr[es ? 2 : 0];
    const float dv = (float)xr[3], mv = (float)xr[4];
    const int j = 2 * jj;
    float2 fd = *(const float2*)&d_frq[(size_t)e * 256 + j];
    float2 pd = *(const float2*)&d_phi[(size_t)e * 256 + j];
    float2 fm = *(const float2*)&m_frq[(size_t)e * 256 + j];
    float2 pm = *(const float2*)&m_phi[(size_t)e * 256 + j];
    const int ja = j & 127;
    float2 ad = *(const float2*)&d_amp[(size_t)e * 128 + ja];
    float2 am = *(const float2*)&m_amp[(size_t)e * 128 + ja];
    float a0 = fmaf(dv, fd.x, pd.x), a1 = fmaf(dv, fd.y, pd.y);
    float b0 = fmaf(mv, fm.x, pm.x), b1 = fmaf(mv, fm.y, pm.y);
    float t0, t1, u0, u1;
    if (j < 128) { t0 = __cosf(a0); t1 = __cosf(a1); u0 = __cosf(b0); u1 = __cosf(b1); }
    else         { t0 = __sinf(a0); t1 = __sinf(a1); u0 = __sinf(b0); u1 = __sinf(b1); }
    float v0 = fmaf(ad.x, t0, am.x * u0);
    float v1 = fmaf(ad.y, t1, am.y * u1);
    *(uint32_t*)&stbuf[(size_t)ee * 256 + j] = f2bf_u(v0) | (f2bf_u(v1) << 16);
  } else if (bid < NH_BLK + NS_BLK + NT_BLK) {
    // ---- tab frags: value(k,c) = k<1000 ? (c<128 ? cos : sin)(k*f_{c&127}) : 0
    const int fragid = (bid - NH_BLK - NS_BLK) * 4 + sub;   // kt*16+nt
    const int kt = fragid >> 4, nt = fragid & 15;
    const int c = nt * 16 + (l & 15);
    const float f = exp2f(-(float)(c & 127) * (13.287712379549449f / 128.f));
    __align__(16) unsigned short v[8];
    #pragma unroll
    for (int j = 0; j < 8; ++j) {
      int k = kt * 32 + ((l >> 4) << 3) + j;
      float val = 0.f;
      if (k < 1000) {
        float s, cv;
        sincosf((float)k * f, &s, &cv);
        val = (c < 128) ? cv : s;
      }
      v[j] = f2bf(val);
    }
    ((uint4*)tf)[fragid * 64 + l] = *(const uint4*)v;
  } else {
    // ---- Wcat frags: Wcat[k][c] = c<128 ? s(k)*w_e[k][c] : -s(k)*w_e[k^256][c-128]
    const int fragid = (bid - NH_BLK - NS_BLK - NT_BLK) * 4 + sub;
    const int kk = fragid >> 4, nt = fragid & 15;
    const int c = nt * 16 + (l & 15);
    __align__(16) unsigned short v[8];
    #pragma unroll
    for (int j = 0; j < 8; ++j) {
      int k = kk * 32 + ((l >> 4) << 3) + j;
      float s = (k < 256) ? 1.f : -1.f;
      float val = (c < 128) ? s * w_e[k * 128 + c]
                            : -s * w_e[(k ^ 256) * 128 + (c - 128)];
      v[j] = f2bf(val);
    }
    ((uint4*)wcat)[fragid * 64 + l] = *(const uint4*)v;
  }
}

// ---------------------------------------------------------------------------
// Stage 2 (fused GEMM + score): for 64 ent-rows per block,
//   Pfull = [e_emb_bf16(512) | H(1024)] @ [Wcat ; tab]   (K = 1536, N = 256)
// then sc_rel from acc fragments (intra-lane row-pair diffs) and sc_abs from
// e_emb(f32, L2-hot) / stbuf / r_emb. Grid: 256 blocks x 256 threads (4 waves).
__global__ __launch_bounds__(256) void kge_fused(
    const int* __restrict__ x, const float* __restrict__ e_emb,
    const float* __restrict__ r_emb,
    const unsigned short* __restrict__ stbuf, const unsigned short* __restrict__ H,
    const unsigned short* __restrict__ wcat, const unsigned short* __restrict__ tf,
    float* __restrict__ out) {
  __shared__ __align__(16) uint4 bb[2][1024];   // B double-buffer, 32 KB
  __shared__ float srl[4][8];
  const int tid = threadIdx.x;
  const int w = tid >> 6, l = tid & 63;
  const int m0 = blockIdx.x * 64 + w * 16;      // wave's ent-row base

  // A source for this lane: ent-row rea = m0 + (l&15)
  const int rea = m0 + (l & 15);
  const int e_a = x[(size_t)(rea >> 1) * XSTR + ((rea & 1) ? 2 : 0)];
  const float* aposf = e_emb + (size_t)e_a * 512 + ((l >> 4) << 3);
  const unsigned short* aposh = H + (size_t)rea * KH + ((l >> 4) << 3);

  float4v acc[16];
  #pragma unroll
  for (int i = 0; i < 16; ++i) acc[i] = (float4v){0, 0, 0, 0};

  const uint4* wq = (const uint4*)wcat;   // frag-contiguous: kstep*1024 + idx
  const uint4* tq = (const uint4*)tf;

  // prologue: stage B(kt=0), load A(0)
  #pragma unroll
  for (int q = 0; q < 4; ++q) bb[0][q * 256 + tid] = wq[q * 256 + tid];
  short8v a_cur;
  {
    float4 v0 = *(const float4*)(aposf + 0);
    float4 v1 = *(const float4*)(aposf + 4);
    a_cur = cvt8(v0, v1);
  }

  for (int kt = 0; kt < 48; ++kt) {
    const int cur = kt & 1;
    uint4 rg0, rg1, rg2, rg3;
    short8v a_nxt;
    if (kt < 47) {
      const int kn = kt + 1;
      const uint4* src = (kn < 16) ? (wq + (size_t)kn * 1024)
                                   : (tq + (size_t)(kn - 16) * 1024);
      rg0 = src[0 * 256 + tid]; rg1 = src[1 * 256 + tid];
      rg2 = src[2 * 256 + tid]; rg3 = src[3 * 256 + tid];
      if (kn < 16) {
        float4 v0 = *(const float4*)(aposf + kn * 32);
        float4 v1 = *(const float4*)(aposf + kn * 32 + 4);
        a_nxt = cvt8(v0, v1);
      } else {
        a_nxt = *(const short8v*)(aposh + (kn - 16) * 32);
      }
    }
    __syncthreads();
    #pragma unroll
    for (int nt = 0; nt < 16; ++nt) {
      short8v b = *(const short8v*)&bb[cur][nt * 64 + l];
      acc[nt] = __builtin_amdgcn_mfma_f32_16x16x32_bf16(a_cur, b, acc[nt], 0, 0, 0);
    }
    if (kt < 47) {
      const int nxt = cur ^ 1;
      bb[nxt][0 * 256 + tid] = rg0; bb[nxt][1 * 256 + tid] = rg1;
      bb[nxt][2 * 256 + tid] = rg2; bb[nxt][3 * 256 + tid] = rg3;
      a_cur = a_nxt;
    }
  }

  // ---- sc_rel from acc: C row = (l>>4)*4 + q, col = nt*16 + (l&15).
  // row pairs (even,odd) are q-pairs (0,1) and (2,3) within the same lane.
  {
    float sr_a = 0.f, sr_b = 0.f;
    #pragma unroll
    for (int nt = 0; nt < 8; ++nt) {
      float drea = acc[nt][0] - acc[nt][1];
      float dima = acc[nt + 8][0] - acc[nt + 8][1];
      sr_a += sqrtf(drea * drea + dima * dima);
      float dreb = acc[nt][2] - acc[nt][3];
      float dimb = acc[nt + 8][2] - acc[nt + 8][3];
      sr_b += sqrtf(dreb * dreb + dimb * dimb);
    }
    #pragma unroll
    for (int off = 1; off < 16; off <<= 1) {
      sr_a += __shfl_xor(sr_a, off);
      sr_b += __shfl_xor(sr_b, off);
    }
    if ((l & 15) == 0) {
      srl[w][(l >> 4) * 2]     = sr_a;   // batch row m0/2 + (l>>4)*2
      srl[w][(l >> 4) * 2 + 1] = sr_b;
    }
  }

  // ---- sc_abs for the wave's 8 batch rows; combine and store ----
  const int brBase = m0 >> 1;
  for (int i = 0; i < 8; ++i) {
    const int br = __builtin_amdgcn_readfirstlane(brBase + i);
    const int* xr = x + (size_t)br * XSTR;
    const int sidx = __builtin_amdgcn_readfirstlane(xr[0]);
    const int ridx = __builtin_amdgcn_readfirstlane(xr[1]);
    const int oidx = __builtin_amdgcn_readfirstlane(xr[2]);
    const float* Es = e_emb + (size_t)sidx * 512;
    const float* Eo = e_emb + (size_t)oidx * 512;
    const unsigned short* Ss = stbuf + (size_t)(2 * br) * 256;
    const unsigned short* So = stbuf + (size_t)(2 * br + 1) * 256;
    float sabs = 0.f;
    #pragma unroll
    for (int u0 = 0; u0 < 384; u0 += 64) {
      const int u = u0 + l;
      float ang = r_emb[(size_t)ridx * 384 + u] * SCALE_ANG;
      float sr = __sinf(ang), cr = __cosf(ang);
      float res, ims, reo, imo;
      if (u0 < 256) {
        res = Es[u]; ims = Es[256 + u];
        reo = Eo[u]; imo = Eo[256 + u];
      } else {
        const int uu = u - 256;
        res = bf1(Ss[uu]); ims = bf1(Ss[128 + uu]);
        reo = bf1(So[uu]); imo = bf1(So[128 + uu]);
      }
      float rsc = res * cr - ims * sr - reo;
      float isc = res * sr + ims * cr - imo;
      sabs += sqrtf(rsc * rsc + isc * isc);
    }
    #pragma unroll
    for (int off = 32; off > 0; off >>= 1) sabs += __shfl_down(sabs, off);
    if (l == 0) out[br] = GAMMA_C - (sabs + srl[w][i]);
  }
}

// ===========================================================================
// Round-3 fallback path (workspace >= 774 KB but < WS_FULL)
#define NTH    512
#define RPB    8
#define ERB    (2*RPB)
#define APAD   520

__global__ void kge_table_old(unsigned short* __restrict__ tab) {
  int t = blockIdx.x;
  int j = threadIdx.x;
  double f = pow(10000.0, -(double)j / 128.0);
  double ang = (double)t * f;
  int q = j >> 1, lo = j & 1;
  tab[t * 256 + 4 * q + lo]     = f2bf((float)cos(ang));
  tab[t * 256 + 4 * q + 2 + lo] = f2bf((float)sin(ang));
}

__global__ void kge_wcat_old(const float* __restrict__ w_e, unsigned short* __restrict__ wcat) {
  int bid = blockIdx.x;
  int kk = bid >> 4, nt = bid & 15;
  int l = threadIdx.x;
  __align__(16) unsigned short v[8];
  int c = nt * 16 + (l & 15);
  #pragma unroll
  for (int j = 0; j < 8; ++j) {
    int k = kk * 32 + ((l >> 4) << 3) + j;
    float s = (k < 256) ? 1.f : -1.f;
    float val = (c < 128) ? s * w_e[k * 128 + c]
                          : -s * w_e[(k ^ 256) * 128 + (c - 128)];
    v[j] = f2bf(val);
  }
  ((uint4*)wcat)[bid * 64 + l] = *(const uint4*)v;
}

__global__ __launch_bounds__(NTH, 4) void kge_main3(
    const int* __restrict__ x,
    const float* __restrict__ e_emb, const float* __restrict__ r_emb,
    const float* __restrict__ d_frq, const float* __restrict__ d_phi, const float* __restrict__ d_amp,
    const float* __restrict__ m_frq, const float* __restrict__ m_phi, const float* __restrict__ m_amp,
    const float* __restrict__ w_rp,
    const unsigned short* __restrict__ tab, const unsigned short* __restrict__ wcat,
    float* __restrict__ out) {
  __shared__ __align__(16) unsigned short A[ERB][APAD];
  __shared__ __align__(16) unsigned short stb[ERB][256];
  __shared__ __align__(16) float p[ERB][256];
  __shared__ int meta[RPB][6];

  const int tid = threadIdx.x;
  const int base_row = blockIdx.x * RPB;
  const int w = tid >> 6, l = tid & 63;

  if (tid < RPB * 6) {
    int r = tid / 6, f = tid % 6;
    meta[r][f] = x[(size_t)(base_row + r) * XSTR + f];
  }
  __syncthreads();

  for (int i = tid; i < ERB * 128; i += NTH) {
    int er = i >> 7, k4 = i & 127;
    int e = (er & 1) ? meta[er >> 1][2] : meta[er >> 1][0];
    float4 v = ((const float4*)e_emb)[(size_t)e * 128 + k4];
    uint2 pk;
    pk.x = f2bf_u(v.x) | (f2bf_u(v.y) << 16);
    pk.y = f2bf_u(v.z) | (f2bf_u(v.w) << 16);
    *(uint2*)&A[er][k4 * 4] = pk;
  }
  for (int it = tid; it < ERB * 256; it += NTH) {
    int j = it & 255, er = it >> 8, r = er >> 1;
    int e = (er & 1) ? meta[r][2] : meta[r][0];
    float dv = (float)meta[r][3], mv = (float)meta[r][4];
    size_t b256 = (size_t)e * 256 + j, b128 = (size_t)e * 128 + (j & 127);
    float argd = fmaf(dv, d_frq[b256], d_phi[b256]);
    float argm = fmaf(mv, m_frq[b256], m_phi[b256]);
    float vd = (j < 128) ? d_amp[b128] * __cosf(argd) : d_amp[b128] * __sinf(argd);
    float vm = (j < 128) ? m_amp[b128] * __cosf(argm) : m_amp[b128] * __sinf(argm);
    stb[er][j] = f2bf(vd + vm);
  }

  float s0 = 0, s1 = 0, s2 = 0, s3 = 0, o0 = 0, o1 = 0, o2 = 0, o3 = 0;
  {
    const int wu  = __builtin_amdgcn_readfirstlane(w);
    const int rid = __builtin_amdgcn_readfirstlane(meta[wu][1]);
    const int*   cp = x + (size_t)(base_row + wu) * XSTR + 6;
    const float* wp = w_rp + (size_t)rid * 200;
    const uint2* tl = ((const uint2*)tab) + l;
    #pragma unroll 2
    for (int n = 0; n < 200; ++n) {
      float wv = wp[n];
      int cS = cp[n];
      int cO = cp[200 + n];
      uint2 qs = tl[(size_t)cS * 64];
      uint2 qo = tl[(size_t)cO * 64];
      s0 = fmaf(wv, bfLo(qs.x), s0); s1 = fmaf(wv, bfHi(qs.x), s1);
      s2 = fmaf(wv, bfLo(qs.y), s2); s3 = fmaf(wv, bfHi(qs.y), s3);
      o0 = fmaf(wv, bfLo(qo.x), o0); o1 = fmaf(wv, bfHi(qo.x), o1);
      o2 = fmaf(wv, bfLo(qo.y), o2); o3 = fmaf(wv, bfHi(qo.y), o3);
    }
  }
  __syncthreads();

  {
    float4v acc0 = {0, 0, 0, 0}, acc1 = {0, 0, 0, 0};
    const int nt0 = 2 * w, nt1 = 2 * w + 1;
    const short8v* bp = (const short8v*)wcat;
    const unsigned short* arow = &A[l & 15][(l >> 4) << 3];
    #pragma unroll 8
    for (int kk = 0; kk < 16; ++kk) {
      short8v a  = *(const short8v*)(arow + kk * 32);
      short8v b0 = bp[(kk * 16 + nt0) * 64 + l];
      short8v b1 = bp[(kk * 16 + nt1) * 64 + l];
      acc0 = __builtin_amdgcn_mfma_f32_16x16x32_bf16(a, b0, acc0, 0, 0, 0);
      acc1 = __builtin_amdgcn_mfma_f32_16x16x32_bf16(a, b1, acc1, 0, 0, 0);
    }
    int col = l & 15, rbase = (l >> 4) * 4;
    #pragma unroll
    for (int q = 0; q < 4; ++q) {
      p[rbase + q][nt0 * 16 + col] = acc0[q];
      p[rbase + q][nt1 * 16 + col] = acc1[q];
    }
  }
  __syncthreads();

  {
    int es = 2 * w, eo = 2 * w + 1;
    p[es][2 * l] += s0; p[es][2 * l + 1] += s1;
    p[es][128 + 2 * l] += s2; p[es][129 + 2 * l] += s3;
    p[eo][2 * l] += o0; p[eo][2 * l + 1] += o1;
    p[eo][128 + 2 * l] += o2; p[eo][129 + 2 * l] += o3;
  }
  __syncthreads();

  {
    int r = w;
    int rid = meta[r][1];
    float sabs = 0.f;
    #pragma unroll
    for (int u0 = 0; u0 < 384; u0 += 64) {
      int u = u0 + l;
      float ang = r_emb[(size_t)rid * 384 + u] * SCALE_ANG;
      float sr = __sinf(ang), cr = __cosf(ang);
      float res, ims, reo, imo;
      if (u < 256) {
        res = bf1(A[2 * r][u]);       ims = bf1(A[2 * r][256 + u]);
        reo = bf1(A[2 * r + 1][u]);   imo = bf1(A[2 * r + 1][256 + u]);
      } else {
        int uu = u - 256;
        res = bf1(stb[2 * r][uu]);     ims = bf1(stb[2 * r][128 + uu]);
        reo = bf1(stb[2 * r + 1][uu]); imo = bf1(stb[2 * r + 1][128 + uu]);
      }
      float rsc = res * cr - ims * sr - reo;
      float isc = res * sr + ims * cr - imo;
      sabs += sqrtf(rsc * rsc + isc * isc);
    }
    float srel = 0.f;
    #pragma unroll
    for (int u0 = 0; u0 < 128; u0 += 64) {
      int u = u0 + l;
      float dre = p[2 * r][u] - p[2 * r + 1][u];
      float dim = p[2 * r][128 + u] - p[2 * r + 1][128 + u];
      srel += sqrtf(dre * dre + dim * dim);
    }
    float tot = sabs + srel;
    #pragma unroll
    for (int off = 32; off > 0; off >>= 1) tot += __shfl_down(tot, off);
    if (l == 0) out[base_row + r] = GAMMA_C - tot;
  }
}

// ===========================================================================
extern "C" void kernel_launch(void* const* d_in, const int* in_sizes, int n_in,
                              void* d_out, int out_size, void* d_ws, size_t ws_size,
                              hipStream_t stream) {
  (void)in_sizes; (void)n_in; (void)out_size;
  const int*   x     = (const int*)d_in[0];
  const float* e_emb = (const float*)d_in[1];
  const float* r_emb = (const float*)d_in[2];
  const float* d_frq = (const float*)d_in[3];
  const float* d_phi = (const float*)d_in[4];
  const float* d_amp = (const float*)d_in[5];
  const float* m_frq = (const float*)d_in[6];
  const float* m_phi = (const float*)d_in[7];
  const float* m_amp = (const float*)d_in[8];
  const float* w_e   = (const float*)d_in[9];
  const float* w_rp  = (const float*)d_in[10];
  float* out = (float*)d_out;

  if (ws_size >= WS_FULL) {
    char* base = (char*)d_ws;
    unsigned short* tf    = (unsigned short*)base;
    unsigned short* wcat  = (unsigned short*)(base + TF_BYTES);
    unsigned short* H     = (unsigned short*)(base + TF_BYTES + WCAT_BYTES);
    unsigned short* stbuf = (unsigned short*)(base + TF_BYTES + WCAT_BYTES + H_BYTES);
    kge_prep<<<dim3(NPREP), dim3(256), 0, stream>>>(
        x, w_rp, w_e, d_frq, d_phi, d_amp, m_frq, m_phi, m_amp,
        tf, wcat, H, stbuf);
    kge_fused<<<dim3(256), dim3(256), 0, stream>>>(
        x, e_emb, r_emb, stbuf, H, wcat, tf, out);
  } else if (ws_size >= WS_OLD) {
    unsigned short* tab  = (unsigned short*)d_ws;
    unsigned short* wcat = (unsigned short*)((char*)d_ws + OLDTAB_BYTES);
    kge_table_old<<<dim3(1000), dim3(128), 0, stream>>>(tab);
    kge_wcat_old<<<dim3(256), dim3(64), 0, stream>>>(w_e, wcat);
    kge_main3<<<dim3(B_ROWS / RPB), dim3(NTH), 0, stream>>>(
        x, e_emb, r_emb, d_frq, d_phi, d_amp, m_frq, m_phi, m_amp, w_rp,
        tab, wcat, out);
  }
}